// Round 3
// baseline (196.312 us; speedup 1.0000x reference)
//
#include <hip/hip_runtime.h>
#include <hip/hip_bf16.h>

#define HWD 128
#define NCH 64
#define NK  9

typedef __attribute__((ext_vector_type(8))) short s16x8;
typedef __attribute__((ext_vector_type(4))) float f32x4;

__device__ __forceinline__ float bf2f(short s) {
  union { unsigned u; float f; } cv;
  cv.u = ((unsigned)(unsigned short)s) << 16;
  return cv.f;
}
__device__ __forceinline__ short f2bf(float f) {
  union { float f; unsigned u; } cv; cv.f = f;
  unsigned r = cv.u + 0x7fffu + ((cv.u >> 16) & 1u);
  return (short)(r >> 16);
}

// ---- w_def [64 o][64 c][3][3] f32  ->  wbt [9 k][64 o][64 c] bf16 ----
__global__ void prep_w_kernel(const float* __restrict__ wd, short* __restrict__ wbt) {
  int i = blockIdx.x * 256 + threadIdx.x;
  if (i >= NK * 64 * 64) return;
  int c = i & 63;
  int o = (i >> 6) & 63;
  int k = i >> 12;
  wbt[i] = f2bf(wd[(o * 64 + c) * 9 + k]);
}

// ---- w_off [18 o][64 c][3][3] f32 -> wbo [9 k][32 o_pad][64 c] bf16 ----
__global__ void prep_wo_kernel(const float* __restrict__ wo, short* __restrict__ wbo) {
  int i = blockIdx.x * 256 + threadIdx.x;
  if (i >= NK * 32 * 64) return;
  int c = i & 63;
  int o = (i >> 6) & 31;
  int k = i >> 11;
  wbo[i] = (o < 18) ? f2bf(wo[(o * 64 + c) * 9 + k]) : (short)0;
}

// ---- x NCHW f32 -> xt NHWC bf16 ----
__global__ __launch_bounds__(256) void transpose_x_kernel(const float* __restrict__ x,
                                                          short* __restrict__ xt) {
  __shared__ float tile[64][129];
  int bid = blockIdx.x;
  int b = bid >> 7, h = bid & 127;
  int t = threadIdx.x;
  const float* xb = x + ((size_t)b * NCH) * HWD * HWD + (size_t)h * HWD;
  #pragma unroll 4
  for (int i = 0; i < 32; ++i) {
    int c = (t >> 7) + 2 * i;
    int w = t & 127;
    tile[c][w] = xb[(size_t)c * HWD * HWD + w];
  }
  __syncthreads();
  short* xto = xt + (((size_t)b * HWD + h) * HWD) * NCH;
  #pragma unroll 4
  for (int i = 0; i < 32; ++i) {
    int idx = i * 256 + t;
    int c = idx & 63, w = idx >> 6;
    xto[(size_t)w * NCH + c] = f2bf(tile[c][w]);
  }
}

// ---- offset conv via MFMA (A = pixels from global, B = weights). No LDS. ----
__global__ __launch_bounds__(256) void off_conv_mfma_kernel(
    const short* __restrict__ xt, const short* __restrict__ wbo,
    const float* __restrict__ bo, float* __restrict__ off)
{
  int bid = blockIdx.x;
  int cid = (bid & 7) * 256 + (bid >> 3);   // XCD swizzle (bijective, 2048 % 8 == 0)
  int wseg = cid & 1;
  int h = (cid >> 1) & 127;
  int b = cid >> 8;
  int w0 = wseg * 64;

  int t = threadIdx.x;
  int lane = t & 63;
  int wv = t >> 6;

  int arow = wv * 16 + (lane & 15);      // pixel row of A fragment (0..63)
  int ahalf = (lane >> 4) * 8;           // K sub-offset within 32-block

  f32x4 acc[2];
  acc[0] = (f32x4){0.f, 0.f, 0.f, 0.f};
  acc[1] = (f32x4){0.f, 0.f, 0.f, 0.f};

  const short* xtb = xt + ((size_t)b * HWD * HWD) * NCH;
  const s16x8 zv = (s16x8){0,0,0,0,0,0,0,0};

  #pragma unroll
  for (int k = 0; k < NK; ++k) {
    int ky = k / 3, kx = k - ky * 3;
    int y = h - 1 + ky;
    int xx = w0 + arow - 1 + kx;
    bool ok = (y >= 0) & (y < HWD) & (xx >= 0) & (xx < HWD);
    int yc = min(max(y, 0), HWD - 1);
    int xc = min(max(xx, 0), HWD - 1);
    const short* asrc = xtb + (size_t)(yc * HWD + xc) * NCH + ahalf;

    s16x8 afr[2];
    #pragma unroll
    for (int s = 0; s < 2; ++s) {
      s16x8 a = *(const s16x8*)(asrc + s * 32);
      afr[s] = ok ? a : zv;
    }

    #pragma unroll
    for (int nt = 0; nt < 2; ++nt) {
      int o = nt * 16 + (lane & 15);
      #pragma unroll
      for (int s = 0; s < 2; ++s) {
        s16x8 bfr = *(const s16x8*)(wbo + ((k * 32 + o) * 64 + s * 32 + ahalf));
        acc[nt] = __builtin_amdgcn_mfma_f32_16x16x32_bf16(afr[s], bfr, acc[nt], 0, 0, 0);
      }
    }
  }

  int pbase = w0 + wv * 16 + (lane >> 4) * 4;
  #pragma unroll
  for (int nt = 0; nt < 2; ++nt) {
    int o = nt * 16 + (lane & 15);
    if (o < 18) {
      float bias = bo[o];
      f32x4 r = acc[nt];
      r[0] += bias; r[1] += bias; r[2] += bias; r[3] += bias;
      float* dst = off + (((size_t)b * 18 + o) * HWD + h) * HWD + pbase;
      *(f32x4*)dst = r;
    }
  }
}

// ---- main deformable conv v3: per-lane gather IS the MFMA B-fragment. ----
// A = weights (row=oc), B = gathered pixels (col=pixel, K=channel). Zero per-tap
// LDS, zero per-tap barriers; waves fully independent until the store epilogue.
__global__ __launch_bounds__(256) void deform_main_kernel(
    const float* __restrict__ off, const short* __restrict__ xt,
    const short* __restrict__ wbt, float* __restrict__ out)
{
  __shared__ float ost[64 * 65];          // epilogue staging only (16.6 KB)

  int bid = blockIdx.x;
  int cid = (bid & 7) * 256 + (bid >> 3); // XCD swizzle: image b -> one XCD (2 MB, L2-fits)
  int wseg = cid & 1;
  int h = (cid >> 1) & 127;
  int b = cid >> 8;
  int w0 = wseg * 64;

  int t = threadIdx.x;
  int lane = t & 63;
  int wv = t >> 6;
  int pl = lane & 15;            // pixel within wave's 16-px tile
  int ch0 = (lane >> 4) * 8;     // this lane's channel chunk (B-frag K offset)

  int w = w0 + wv * 16 + pl;     // global pixel column

  f32x4 acc[4];
  #pragma unroll
  for (int nt = 0; nt < 4; ++nt) acc[nt] = (f32x4){0.f, 0.f, 0.f, 0.f};

  const short* xtb = xt + ((size_t)b * HWD * HWD) * NCH;
  const float* offp = off + (size_t)b * 18 * HWD * HWD + (size_t)h * HWD + w;

  #pragma unroll
  for (int k = 0; k < NK; ++k) {
    // offsets for this pixel/tap (lanes 16+ duplicate lanes 0-15 -> broadcast loads)
    float offy = offp[(size_t)(2 * k) * HWD * HWD];
    float offx = offp[(size_t)(2 * k + 1) * HWD * HWD];
    int ky = k / 3, kx = k - ky * 3;
    float py = offy + (float)(h - 1 + ky);
    float px = offx + (float)(w - 1 + kx);
    float y0f = floorf(py), x0f = floorf(px);
    float wy1 = py - y0f, wx1 = px - x0f;
    float wy0 = 1.f - wy1, wx0 = 1.f - wx1;
    int y0 = (int)y0f, x0 = (int)x0f;

    float v0[8], v1[8];
    #pragma unroll
    for (int j = 0; j < 8; ++j) { v0[j] = 0.f; v1[j] = 0.f; }

    #pragma unroll
    for (int cy = 0; cy < 2; ++cy) {
      #pragma unroll
      for (int cx = 0; cx < 2; ++cx) {
        int yy = y0 + cy, xx = x0 + cx;
        float wt = (cy ? wy1 : wy0) * (cx ? wx1 : wx0);
        bool ok = (yy >= 0) & (yy < HWD) & (xx >= 0) & (xx < HWD);
        float wz = ok ? wt : 0.f;
        int yc = min(max(yy, 0), HWD - 1);
        int xc = min(max(xx, 0), HWD - 1);
        const short* src = xtb + (size_t)(yc * HWD + xc) * NCH + ch0;
        s16x8 r0 = *(const s16x8*)(src);        // channels ch0..ch0+8
        s16x8 r1 = *(const s16x8*)(src + 32);   // channels ch0+32..+40
        #pragma unroll
        for (int j = 0; j < 8; ++j) {
          v0[j] += wz * bf2f(r0[j]);
          v1[j] += wz * bf2f(r1[j]);
        }
      }
    }

    // pack: these ARE the B-fragments (col=pixel pl, k=channel)
    s16x8 bfr0, bfr1;
    #pragma unroll
    for (int j = 0; j < 8; ++j) { bfr0[j] = f2bf(v0[j]); bfr1[j] = f2bf(v1[j]); }

    // A-fragments = weights (row=oc, k=channel), L2/L1-hot broadcast
    #pragma unroll
    for (int nt = 0; nt < 4; ++nt) {
      int o = nt * 16 + pl;
      s16x8 a0 = *(const s16x8*)(wbt + ((k * 64 + o) * 64 + ch0));
      s16x8 a1 = *(const s16x8*)(wbt + ((k * 64 + o) * 64 + ch0 + 32));
      acc[nt] = __builtin_amdgcn_mfma_f32_16x16x32_bf16(a0, bfr0, acc[nt], 0, 0, 0);
      acc[nt] = __builtin_amdgcn_mfma_f32_16x16x32_bf16(a1, bfr1, acc[nt], 0, 0, 0);
    }
  }

  // ---- epilogue: D has col=pixel (lane&15), row=oc ((lane>>4)*4+r+16nt).
  // Stage through LDS once for coalesced 256B NCHW stores.
  #pragma unroll
  for (int nt = 0; nt < 4; ++nt) {
    int oc = nt * 16 + (lane >> 4) * 4;
    #pragma unroll
    for (int r = 0; r < 4; ++r)
      ost[(oc + r) * 65 + wv * 16 + pl] = acc[nt][r];
  }
  __syncthreads();
  float* ob = out + ((size_t)(b * NCH) * HWD + h) * HWD + w0;
  #pragma unroll
  for (int i = 0; i < 16; ++i) {
    int idx = i * 256 + t;
    int px = idx & 63, oc = idx >> 6;
    ob[(size_t)oc * HWD * HWD + px] = ost[oc * 65 + px];
  }
}

extern "C" void kernel_launch(void* const* d_in, const int* in_sizes, int n_in,
                              void* d_out, int out_size, void* d_ws, size_t ws_size,
                              hipStream_t stream) {
  const float* x     = (const float*)d_in[0];
  const float* w_off = (const float*)d_in[1];
  const float* b_off = (const float*)d_in[2];
  const float* w_def = (const float*)d_in[3];
  float* out = (float*)d_out;

  char* ws = (char*)d_ws;
  float* off_ws = (float*)ws;                          // 8*18*128*128*4 = 9,437,184 B
  short* xt     = (short*)(ws + 9437184);              // 8*128*128*64*2 = 16,777,216 B
  short* wbt    = (short*)(ws + 9437184 + 16777216);   // 9*64*64*2      =     73,728 B
  short* wbo    = (short*)(ws + 9437184 + 16777216 + 73728); // 9*32*64*2 = 36,864 B

  hipLaunchKernelGGL(prep_w_kernel,       dim3(144),  dim3(256), 0, stream, w_def, wbt);
  hipLaunchKernelGGL(prep_wo_kernel,      dim3(72),   dim3(256), 0, stream, w_off, wbo);
  hipLaunchKernelGGL(transpose_x_kernel,  dim3(1024), dim3(256), 0, stream, x, xt);
  hipLaunchKernelGGL(off_conv_mfma_kernel,dim3(2048), dim3(256), 0, stream, xt, wbo, b_off, off_ws);
  hipLaunchKernelGGL(deform_main_kernel,  dim3(2048), dim3(256), 0, stream, off_ws, xt, wbt, out);
}

// Round 4
// 196.297 us; speedup vs baseline: 1.0001x; 1.0001x over previous
//
#include <hip/hip_runtime.h>
#include <hip/hip_bf16.h>

#define HWD 128
#define NCH 64
#define NK  9

typedef __attribute__((ext_vector_type(8))) short s16x8;
typedef __attribute__((ext_vector_type(4))) float f32x4;

__device__ __forceinline__ float bf2f(short s) {
  union { unsigned u; float f; } cv;
  cv.u = ((unsigned)(unsigned short)s) << 16;
  return cv.f;
}
__device__ __forceinline__ short f2bf(float f) {
  union { float f; unsigned u; } cv; cv.f = f;
  unsigned r = cv.u + 0x7fffu + ((cv.u >> 16) & 1u);
  return (short)(r >> 16);
}

// ---- w_def [64 o][64 c][3][3] f32  ->  wbt [9 k][64 o][64 c] bf16 ----
__global__ void prep_w_kernel(const float* __restrict__ wd, short* __restrict__ wbt) {
  int i = blockIdx.x * 256 + threadIdx.x;
  if (i >= NK * 64 * 64) return;
  int c = i & 63;
  int o = (i >> 6) & 63;
  int k = i >> 12;
  wbt[i] = f2bf(wd[(o * 64 + c) * 9 + k]);
}

// ---- w_off [18 o][64 c][3][3] f32 -> wbo [9 k][32 o_pad][64 c] bf16 ----
__global__ void prep_wo_kernel(const float* __restrict__ wo, short* __restrict__ wbo) {
  int i = blockIdx.x * 256 + threadIdx.x;
  if (i >= NK * 32 * 64) return;
  int c = i & 63;
  int o = (i >> 6) & 31;
  int k = i >> 11;
  wbo[i] = (o < 18) ? f2bf(wo[(o * 64 + c) * 9 + k]) : (short)0;
}

// ---- x NCHW f32 -> xt NHWC bf16 ----
__global__ __launch_bounds__(256) void transpose_x_kernel(const float* __restrict__ x,
                                                          short* __restrict__ xt) {
  __shared__ float tile[64][129];
  int bid = blockIdx.x;
  int b = bid >> 7, h = bid & 127;
  int t = threadIdx.x;
  const float* xb = x + ((size_t)b * NCH) * HWD * HWD + (size_t)h * HWD;
  #pragma unroll 4
  for (int i = 0; i < 32; ++i) {
    int c = (t >> 7) + 2 * i;
    int w = t & 127;
    tile[c][w] = xb[(size_t)c * HWD * HWD + w];
  }
  __syncthreads();
  short* xto = xt + (((size_t)b * HWD + h) * HWD) * NCH;
  #pragma unroll 4
  for (int i = 0; i < 32; ++i) {
    int idx = i * 256 + t;
    int c = idx & 63, w = idx >> 6;
    xto[(size_t)w * NCH + c] = f2bf(tile[c][w]);
  }
}

// ---- offset conv via MFMA (A = pixels from global, B = weights). No LDS. ----
__global__ __launch_bounds__(256) void off_conv_mfma_kernel(
    const short* __restrict__ xt, const short* __restrict__ wbo,
    const float* __restrict__ bo, float* __restrict__ off)
{
  int bid = blockIdx.x;
  int cid = (bid & 7) * 256 + (bid >> 3);   // XCD swizzle (bijective, 2048 % 8 == 0)
  int wseg = cid & 1;
  int h = (cid >> 1) & 127;
  int b = cid >> 8;
  int w0 = wseg * 64;

  int t = threadIdx.x;
  int lane = t & 63;
  int wv = t >> 6;

  int arow = wv * 16 + (lane & 15);
  int ahalf = (lane >> 4) * 8;

  f32x4 acc[2];
  acc[0] = (f32x4){0.f, 0.f, 0.f, 0.f};
  acc[1] = (f32x4){0.f, 0.f, 0.f, 0.f};

  const short* xtb = xt + ((size_t)b * HWD * HWD) * NCH;
  const s16x8 zv = (s16x8){0,0,0,0,0,0,0,0};

  #pragma unroll
  for (int k = 0; k < NK; ++k) {
    int ky = k / 3, kx = k - ky * 3;
    int y = h - 1 + ky;
    int xx = w0 + arow - 1 + kx;
    bool ok = (y >= 0) & (y < HWD) & (xx >= 0) & (xx < HWD);
    int yc = min(max(y, 0), HWD - 1);
    int xc = min(max(xx, 0), HWD - 1);
    const short* asrc = xtb + (size_t)(yc * HWD + xc) * NCH + ahalf;

    s16x8 afr[2];
    #pragma unroll
    for (int s = 0; s < 2; ++s) {
      s16x8 a = *(const s16x8*)(asrc + s * 32);
      afr[s] = ok ? a : zv;
    }

    #pragma unroll
    for (int nt = 0; nt < 2; ++nt) {
      int o = nt * 16 + (lane & 15);
      #pragma unroll
      for (int s = 0; s < 2; ++s) {
        s16x8 bfr = *(const s16x8*)(wbo + ((k * 32 + o) * 64 + s * 32 + ahalf));
        acc[nt] = __builtin_amdgcn_mfma_f32_16x16x32_bf16(afr[s], bfr, acc[nt], 0, 0, 0);
      }
    }
  }

  int pbase = w0 + wv * 16 + (lane >> 4) * 4;
  #pragma unroll
  for (int nt = 0; nt < 2; ++nt) {
    int o = nt * 16 + (lane & 15);
    if (o < 18) {
      float bias = bo[o];
      f32x4 r = acc[nt];
      r[0] += bias; r[1] += bias; r[2] += bias; r[3] += bias;
      float* dst = off + (((size_t)b * 18 + o) * HWD + h) * HWD + pbase;
      *(f32x4*)dst = r;
    }
  }
}

// ---- main deformable conv v4: 1-wave blocks, register double-buffered
// software pipeline. Per tap: prefetch raw corners (tap k) + offsets (k+1)
// BEFORE consuming tap k-1 (interp+pack+MFMA) -> gather latency hidden. ----
#define PXSTRIDE ((size_t)(HWD * HWD))

__global__ __launch_bounds__(64) void deform_main_kernel(
    const float* __restrict__ off, const short* __restrict__ xt,
    const short* __restrict__ wbt, float* __restrict__ out)
{
  __shared__ float ost[64 * 17];          // 4.25 KB per-wave epilogue staging

  int bid = blockIdx.x;
  int cid = (bid & 7) * 1024 + (bid >> 3);  // XCD swizzle (8192 % 8 == 0, bijective)
  int wseg = cid & 7;
  int h = (cid >> 3) & 127;
  int b = cid >> 10;
  int w0 = wseg * 16;

  int lane = threadIdx.x & 63;
  int pl = lane & 15;            // pixel within 16-px tile
  int ch0 = (lane >> 4) * 8;     // channel chunk (B-frag K offset)
  int w = w0 + pl;

  f32x4 acc[4];
  #pragma unroll
  for (int nt = 0; nt < 4; ++nt) acc[nt] = (f32x4){0.f, 0.f, 0.f, 0.f};

  const short* xtb = xt + ((size_t)b * HWD * HWD) * NCH;
  const float* offp = off + (size_t)b * 18 * PXSTRIDE + (size_t)h * HWD + w;

  // register double buffers (all indices compile-time after unroll)
  s16x8 GA[8], GB[8];
  float wtA[4], wtB[4];

  // prefetch for tap k into (G, wt): raw corner loads + folded bilinear weights
  auto prefetch = [&](int k, s16x8* G, float* wt, float oy, float ox) {
    int ky = k / 3, kx = k - ky * 3;
    float py = oy + (float)(h - 1 + ky);
    float px = ox + (float)(w - 1 + kx);
    float y0f = floorf(py), x0f = floorf(px);
    float wy1 = py - y0f, wx1 = px - x0f;
    float wy0 = 1.f - wy1, wx0 = 1.f - wx1;
    int y0 = (int)y0f, x0 = (int)x0f;
    #pragma unroll
    for (int r = 0; r < 4; ++r) {
      int yy = y0 + (r >> 1), xx = x0 + (r & 1);
      bool ok = (yy >= 0) & (yy < HWD) & (xx >= 0) & (xx < HWD);
      float wv2 = ((r >> 1) ? wy1 : wy0) * ((r & 1) ? wx1 : wx0);
      wt[r] = ok ? wv2 : 0.f;
      int yc = min(max(yy, 0), HWD - 1);
      int xc = min(max(xx, 0), HWD - 1);
      const short* src = xtb + (size_t)(yc * HWD + xc) * NCH + ch0;
      G[2 * r]     = *(const s16x8*)(src);        // channels ch0..+8
      G[2 * r + 1] = *(const s16x8*)(src + 32);   // channels ch0+32..+40
    }
  };

  // consume tap j: interp -> pack bf16 -> 8 MFMAs
  auto consume = [&](int k, const s16x8* G, const float* wt) {
    float v0[8], v1[8];
    #pragma unroll
    for (int j = 0; j < 8; ++j) { v0[j] = 0.f; v1[j] = 0.f; }
    #pragma unroll
    for (int r = 0; r < 4; ++r) {
      float wz = wt[r];
      #pragma unroll
      for (int j = 0; j < 8; ++j) {
        v0[j] += wz * bf2f(G[2 * r][j]);
        v1[j] += wz * bf2f(G[2 * r + 1][j]);
      }
    }
    s16x8 bfr0, bfr1;
    #pragma unroll
    for (int j = 0; j < 8; ++j) { bfr0[j] = f2bf(v0[j]); bfr1[j] = f2bf(v1[j]); }
    #pragma unroll
    for (int nt = 0; nt < 4; ++nt) {
      int o = nt * 16 + pl;
      s16x8 a0 = *(const s16x8*)(wbt + ((k * 64 + o) * 64 + ch0));
      s16x8 a1 = *(const s16x8*)(wbt + ((k * 64 + o) * 64 + ch0 + 32));
      acc[nt] = __builtin_amdgcn_mfma_f32_16x16x32_bf16(a0, bfr0, acc[nt], 0, 0, 0);
      acc[nt] = __builtin_amdgcn_mfma_f32_16x16x32_bf16(a1, bfr1, acc[nt], 0, 0, 0);
    }
  };

  float oy = offp[0];
  float ox = offp[PXSTRIDE];

  #pragma unroll
  for (int k = 0; k < NK; ++k) {
    // issue tap-k gathers + weight calc (uses oy/ox loaded last iter)
    if (k & 1) prefetch(k, GB, wtB, oy, ox);
    else       prefetch(k, GA, wtA, oy, ox);
    // issue next tap's offset loads (latency hidden under consume below)
    if (k < NK - 1) {
      oy = offp[(size_t)(2 * k + 2) * PXSTRIDE];
      ox = offp[(size_t)(2 * k + 3) * PXSTRIDE];
    }
    // consume previous tap while tap-k loads are in flight
    if (k > 0) {
      if (k & 1) consume(k - 1, GA, wtA);
      else       consume(k - 1, GB, wtB);
    }
  }
  consume(NK - 1, GA, wtA);   // tap 8 is even -> in GA

  // ---- epilogue: D col=pixel (lane&15), row=oc ((lane>>4)*4+r+16nt).
  // Stage through per-wave LDS for coalesced NCHW stores.
  #pragma unroll
  for (int nt = 0; nt < 4; ++nt) {
    int oc = nt * 16 + (lane >> 4) * 4;
    #pragma unroll
    for (int r = 0; r < 4; ++r)
      ost[(oc + r) * 17 + pl] = acc[nt][r];
  }
  __syncthreads();
  float* ob = out + ((size_t)(b * NCH) * HWD + h) * HWD + w0;
  #pragma unroll
  for (int i = 0; i < 16; ++i) {
    int oc = i * 4 + (lane >> 4);
    int px = lane & 15;
    ob[(size_t)oc * HWD * HWD + px] = ost[oc * 17 + px];
  }
}

extern "C" void kernel_launch(void* const* d_in, const int* in_sizes, int n_in,
                              void* d_out, int out_size, void* d_ws, size_t ws_size,
                              hipStream_t stream) {
  const float* x     = (const float*)d_in[0];
  const float* w_off = (const float*)d_in[1];
  const float* b_off = (const float*)d_in[2];
  const float* w_def = (const float*)d_in[3];
  float* out = (float*)d_out;

  char* ws = (char*)d_ws;
  float* off_ws = (float*)ws;                          // 8*18*128*128*4 = 9,437,184 B
  short* xt     = (short*)(ws + 9437184);              // 8*128*128*64*2 = 16,777,216 B
  short* wbt    = (short*)(ws + 9437184 + 16777216);   // 9*64*64*2      =     73,728 B
  short* wbo    = (short*)(ws + 9437184 + 16777216 + 73728); // 9*32*64*2 = 36,864 B

  hipLaunchKernelGGL(prep_w_kernel,       dim3(144),  dim3(256), 0, stream, w_def, wbt);
  hipLaunchKernelGGL(prep_wo_kernel,      dim3(72),   dim3(256), 0, stream, w_off, wbo);
  hipLaunchKernelGGL(transpose_x_kernel,  dim3(1024), dim3(256), 0, stream, x, xt);
  hipLaunchKernelGGL(off_conv_mfma_kernel,dim3(2048), dim3(256), 0, stream, xt, wbo, b_off, off_ws);
  hipLaunchKernelGGL(deform_main_kernel,  dim3(8192), dim3(64),  0, stream, off_ws, xt, wbt, out);
}

// Round 5
// 146.212 us; speedup vs baseline: 1.3426x; 1.3425x over previous
//
#include <hip/hip_runtime.h>
#include <hip/hip_bf16.h>

#define HWD 128
#define NCH 64
#define NK  9

typedef __attribute__((ext_vector_type(8))) short s16x8;
typedef __attribute__((ext_vector_type(4))) float f32x4;

__device__ __forceinline__ float bf2f(short s) {
  union { unsigned u; float f; } cv;
  cv.u = ((unsigned)(unsigned short)s) << 16;
  return cv.f;
}
__device__ __forceinline__ short f2bf(float f) {
  union { float f; unsigned u; } cv; cv.f = f;
  unsigned r = cv.u + 0x7fffu + ((cv.u >> 16) & 1u);
  return (short)(r >> 16);
}

// ---- w_def [64 o][64 c][3][3] f32  ->  wbt [9 k][64 o][64 c] bf16 ----
__global__ void prep_w_kernel(const float* __restrict__ wd, short* __restrict__ wbt) {
  int i = blockIdx.x * 256 + threadIdx.x;
  if (i >= NK * 64 * 64) return;
  int c = i & 63;
  int o = (i >> 6) & 63;
  int k = i >> 12;
  wbt[i] = f2bf(wd[(o * 64 + c) * 9 + k]);
}

// ---- w_off [18 o][64 c][3][3] f32 -> wbo [9 k][32 o_pad][64 c] bf16 ----
__global__ void prep_wo_kernel(const float* __restrict__ wo, short* __restrict__ wbo) {
  int i = blockIdx.x * 256 + threadIdx.x;
  if (i >= NK * 32 * 64) return;
  int c = i & 63;
  int o = (i >> 6) & 31;
  int k = i >> 11;
  wbo[i] = (o < 18) ? f2bf(wo[(o * 64 + c) * 9 + k]) : (short)0;
}

// ---- x NCHW f32 -> xt NHWC bf16 ----
__global__ __launch_bounds__(256) void transpose_x_kernel(const float* __restrict__ x,
                                                          short* __restrict__ xt) {
  __shared__ float tile[64][129];
  int bid = blockIdx.x;
  int b = bid >> 7, h = bid & 127;
  int t = threadIdx.x;
  const float* xb = x + ((size_t)b * NCH) * HWD * HWD + (size_t)h * HWD;
  #pragma unroll 4
  for (int i = 0; i < 32; ++i) {
    int c = (t >> 7) + 2 * i;
    int w = t & 127;
    tile[c][w] = xb[(size_t)c * HWD * HWD + w];
  }
  __syncthreads();
  short* xto = xt + (((size_t)b * HWD + h) * HWD) * NCH;
  #pragma unroll 4
  for (int i = 0; i < 32; ++i) {
    int idx = i * 256 + t;
    int c = idx & 63, w = idx >> 6;
    xto[(size_t)w * NCH + c] = f2bf(tile[c][w]);
  }
}

// ---- offset conv via MFMA (A = pixels from global, B = weights). No LDS. ----
__global__ __launch_bounds__(256) void off_conv_mfma_kernel(
    const short* __restrict__ xt, const short* __restrict__ wbo,
    const float* __restrict__ bo, float* __restrict__ off)
{
  int bid = blockIdx.x;
  int cid = (bid & 7) * 256 + (bid >> 3);   // XCD swizzle (bijective, 2048 % 8 == 0)
  int wseg = cid & 1;
  int h = (cid >> 1) & 127;
  int b = cid >> 8;
  int w0 = wseg * 64;

  int t = threadIdx.x;
  int lane = t & 63;
  int wv = t >> 6;

  int arow = wv * 16 + (lane & 15);
  int ahalf = (lane >> 4) * 8;

  f32x4 acc[2];
  acc[0] = (f32x4){0.f, 0.f, 0.f, 0.f};
  acc[1] = (f32x4){0.f, 0.f, 0.f, 0.f};

  const short* xtb = xt + ((size_t)b * HWD * HWD) * NCH;
  const s16x8 zv = (s16x8){0,0,0,0,0,0,0,0};

  #pragma unroll
  for (int k = 0; k < NK; ++k) {
    int ky = k / 3, kx = k - ky * 3;
    int y = h - 1 + ky;
    int xx = w0 + arow - 1 + kx;
    bool ok = (y >= 0) & (y < HWD) & (xx >= 0) & (xx < HWD);
    int yc = min(max(y, 0), HWD - 1);
    int xc = min(max(xx, 0), HWD - 1);
    const short* asrc = xtb + (size_t)(yc * HWD + xc) * NCH + ahalf;

    s16x8 afr[2];
    #pragma unroll
    for (int s = 0; s < 2; ++s) {
      s16x8 a = *(const s16x8*)(asrc + s * 32);
      afr[s] = ok ? a : zv;
    }

    #pragma unroll
    for (int nt = 0; nt < 2; ++nt) {
      int o = nt * 16 + (lane & 15);
      #pragma unroll
      for (int s = 0; s < 2; ++s) {
        s16x8 bfr = *(const s16x8*)(wbo + ((k * 32 + o) * 64 + s * 32 + ahalf));
        acc[nt] = __builtin_amdgcn_mfma_f32_16x16x32_bf16(afr[s], bfr, acc[nt], 0, 0, 0);
      }
    }
  }

  int pbase = w0 + wv * 16 + (lane >> 4) * 4;
  #pragma unroll
  for (int nt = 0; nt < 2; ++nt) {
    int o = nt * 16 + (lane & 15);
    if (o < 18) {
      float bias = bo[o];
      f32x4 r = acc[nt];
      r[0] += bias; r[1] += bias; r[2] += bias; r[3] += bias;
      float* dst = off + (((size_t)b * 18 + o) * HWD + h) * HWD + pbase;
      *(f32x4*)dst = r;
    }
  }
}

// ---- main deformable conv v5: weights staged in LDS (2 stages of 5+4 taps,
// 72-short padded rows), in-register gather = B-frag, all offsets hoisted.
// Halves the TA/L1 scattered-request volume (weights move to the LDS pipe). ----
#define PXSTRIDE ((size_t)(HWD * HWD))
#define WROW 72                       // padded row: 64 ch + 8 pad shorts (144 B)

__global__ __launch_bounds__(256) void deform_main_kernel(
    const float* __restrict__ off, const short* __restrict__ xt,
    const short* __restrict__ wbt, float* __restrict__ out)
{
  __shared__ short wlds[5 * 64 * WROW];   // 46080 B; stage-2 + epilogue reuse

  int bid = blockIdx.x;
  int cid = (bid & 7) * 256 + (bid >> 3); // XCD swizzle (bijective, 2048 % 8 == 0)
  int wseg = cid & 1;
  int h = (cid >> 1) & 127;
  int b = cid >> 8;
  int w0 = wseg * 64;

  int t = threadIdx.x;
  int lane = t & 63;
  int wv = t >> 6;
  int pl = lane & 15;            // pixel within wave's 16-px tile (B-frag col)
  int ch0 = (lane >> 4) * 8;     // channel chunk (K offset)
  int w = w0 + wv * 16 + pl;

  const short* xtb = xt + ((size_t)b * HWD * HWD) * NCH;
  const float* offp = off + (size_t)b * 18 * PXSTRIDE + (size_t)h * HWD + w;

  // ---- hoist ALL 18 offset loads (issue up front, overlap with staging) ----
  float oys[NK], oxs[NK];
  #pragma unroll
  for (int k = 0; k < NK; ++k) {
    oys[k] = offp[(size_t)(2 * k) * PXSTRIDE];
    oxs[k] = offp[(size_t)(2 * k + 1) * PXSTRIDE];
  }

  // ---- stage weights rows [gk0*64, gk0*64+nrows) into padded LDS ----
  auto stage = [&](int gk0, int nrows) {
    const short* gsrc = wbt + (size_t)gk0 * 64 * 64;
    int nchunk = nrows * 9;              // 16B chunks incl. 1 pad chunk per row
    for (int i = 0; i * 256 < nchunk; ++i) {
      int idx = i * 256 + t;
      if (idx < nchunk) {
        int row = idx / 9, ch = idx - row * 9;
        if (ch < 8) {
          s16x8 v = *(const s16x8*)(gsrc + row * 64 + ch * 8);
          *(s16x8*)(wlds + row * WROW + ch * 8) = v;
        }
      }
    }
  };

  f32x4 acc[4];
  #pragma unroll
  for (int nt = 0; nt < 4; ++nt) acc[nt] = (f32x4){0.f, 0.f, 0.f, 0.f};

  // ---- one tap: gather (global, scattered) -> interp -> pack -> 8 MFMAs (A from LDS)
  auto tap = [&](int k, int kloc) {
    int ky = k / 3, kx = k - ky * 3;
    float py = oys[k] + (float)(h - 1 + ky);
    float px = oxs[k] + (float)(w - 1 + kx);
    float y0f = floorf(py), x0f = floorf(px);
    float wy1 = py - y0f, wx1 = px - x0f;
    float wy0 = 1.f - wy1, wx0 = 1.f - wx1;
    int y0 = (int)y0f, x0 = (int)x0f;

    s16x8 G[8];
    float wt[4];
    #pragma unroll
    for (int r = 0; r < 4; ++r) {
      int yy = y0 + (r >> 1), xx = x0 + (r & 1);
      bool ok = (yy >= 0) & (yy < HWD) & (xx >= 0) & (xx < HWD);
      float wv2 = ((r >> 1) ? wy1 : wy0) * ((r & 1) ? wx1 : wx0);
      wt[r] = ok ? wv2 : 0.f;
      int yc = min(max(yy, 0), HWD - 1);
      int xc = min(max(xx, 0), HWD - 1);
      const short* src = xtb + (size_t)(yc * HWD + xc) * NCH + ch0;
      G[2 * r]     = *(const s16x8*)(src);        // channels ch0..+8
      G[2 * r + 1] = *(const s16x8*)(src + 32);   // channels ch0+32..+40
    }

    float v0[8], v1[8];
    #pragma unroll
    for (int j = 0; j < 8; ++j) { v0[j] = 0.f; v1[j] = 0.f; }
    #pragma unroll
    for (int r = 0; r < 4; ++r) {
      float wz = wt[r];
      #pragma unroll
      for (int j = 0; j < 8; ++j) {
        v0[j] += wz * bf2f(G[2 * r][j]);
        v1[j] += wz * bf2f(G[2 * r + 1][j]);
      }
    }
    s16x8 bfr0, bfr1;
    #pragma unroll
    for (int j = 0; j < 8; ++j) { bfr0[j] = f2bf(v0[j]); bfr1[j] = f2bf(v1[j]); }

    const short* wk = wlds + kloc * (64 * WROW);
    #pragma unroll
    for (int nt = 0; nt < 4; ++nt) {
      int o = nt * 16 + pl;
      s16x8 a0 = *(const s16x8*)(wk + o * WROW + ch0);
      s16x8 a1 = *(const s16x8*)(wk + o * WROW + ch0 + 32);
      acc[nt] = __builtin_amdgcn_mfma_f32_16x16x32_bf16(a0, bfr0, acc[nt], 0, 0, 0);
      acc[nt] = __builtin_amdgcn_mfma_f32_16x16x32_bf16(a1, bfr1, acc[nt], 0, 0, 0);
    }
  };

  // ---- stage 1: taps 0-4 ----
  stage(0, 320);
  __syncthreads();
  #pragma unroll
  for (int k = 0; k < 5; ++k) tap(k, k);

  // ---- stage 2: taps 5-8 ----
  __syncthreads();
  stage(5, 256);
  __syncthreads();
  #pragma unroll
  for (int k = 5; k < 9; ++k) tap(k, k - 5);

  // ---- epilogue: D col=pixel (lane&15), row=oc ((lane>>4)*4+r+16nt).
  // Stage through LDS (reusing wlds) for coalesced NCHW stores.
  __syncthreads();
  float* ost = (float*)wlds;   // [64 oc][65]
  #pragma unroll
  for (int nt = 0; nt < 4; ++nt) {
    int oc = nt * 16 + (lane >> 4) * 4;
    #pragma unroll
    for (int r = 0; r < 4; ++r)
      ost[(oc + r) * 65 + wv * 16 + pl] = acc[nt][r];
  }
  __syncthreads();
  float* ob = out + ((size_t)(b * NCH) * HWD + h) * HWD + w0;
  #pragma unroll
  for (int i = 0; i < 16; ++i) {
    int idx = i * 256 + t;
    int px = idx & 63, oc = idx >> 6;
    ob[(size_t)oc * HWD * HWD + px] = ost[oc * 65 + px];
  }
}

extern "C" void kernel_launch(void* const* d_in, const int* in_sizes, int n_in,
                              void* d_out, int out_size, void* d_ws, size_t ws_size,
                              hipStream_t stream) {
  const float* x     = (const float*)d_in[0];
  const float* w_off = (const float*)d_in[1];
  const float* b_off = (const float*)d_in[2];
  const float* w_def = (const float*)d_in[3];
  float* out = (float*)d_out;

  char* ws = (char*)d_ws;
  float* off_ws = (float*)ws;                          // 8*18*128*128*4 = 9,437,184 B
  short* xt     = (short*)(ws + 9437184);              // 8*128*128*64*2 = 16,777,216 B
  short* wbt    = (short*)(ws + 9437184 + 16777216);   // 9*64*64*2      =     73,728 B
  short* wbo    = (short*)(ws + 9437184 + 16777216 + 73728); // 9*32*64*2 = 36,864 B

  hipLaunchKernelGGL(prep_w_kernel,       dim3(144),  dim3(256), 0, stream, w_def, wbt);
  hipLaunchKernelGGL(prep_wo_kernel,      dim3(72),   dim3(256), 0, stream, w_off, wbo);
  hipLaunchKernelGGL(transpose_x_kernel,  dim3(1024), dim3(256), 0, stream, x, xt);
  hipLaunchKernelGGL(off_conv_mfma_kernel,dim3(2048), dim3(256), 0, stream, xt, wbo, b_off, off_ws);
  hipLaunchKernelGGL(deform_main_kernel,  dim3(2048), dim3(256), 0, stream, off_ws, xt, wbt, out);
}

// Round 6
// 86.466 us; speedup vs baseline: 2.2704x; 1.6910x over previous
//
#include <hip/hip_runtime.h>
#include <hip/hip_bf16.h>

#define HWD 128
#define NCH 64
#define NK  9

typedef __attribute__((ext_vector_type(8))) _Float16 h16x8;
typedef __attribute__((ext_vector_type(4))) float f32x4;

// ---- w_def [64 o][64 c][3][3] f32  ->  wbt [9 k][64 o][64 c] fp16 ----
__global__ void prep_w_kernel(const float* __restrict__ wd, _Float16* __restrict__ wbt) {
  int i = blockIdx.x * 256 + threadIdx.x;
  if (i >= NK * 64 * 64) return;
  int c = i & 63;
  int o = (i >> 6) & 63;
  int k = i >> 12;
  wbt[i] = (_Float16)wd[(o * 64 + c) * 9 + k];
}

// ---- w_off [18 o][64 c][3][3] f32 -> wbo [9 k][32 o_pad][64 c] fp16 ----
__global__ void prep_wo_kernel(const float* __restrict__ wo, _Float16* __restrict__ wbo) {
  int i = blockIdx.x * 256 + threadIdx.x;
  if (i >= NK * 32 * 64) return;
  int c = i & 63;
  int o = (i >> 6) & 31;
  int k = i >> 11;
  wbo[i] = (o < 18) ? (_Float16)wo[(o * 64 + c) * 9 + k] : (_Float16)0;
}

// ---- x NCHW f32 -> xt NHWC fp16 ----
__global__ __launch_bounds__(256) void transpose_x_kernel(const float* __restrict__ x,
                                                          _Float16* __restrict__ xt) {
  __shared__ float tile[64][129];
  int bid = blockIdx.x;
  int b = bid >> 7, h = bid & 127;
  int t = threadIdx.x;
  const float* xb = x + ((size_t)b * NCH) * HWD * HWD + (size_t)h * HWD;
  #pragma unroll 4
  for (int i = 0; i < 32; ++i) {
    int c = (t >> 7) + 2 * i;
    int w = t & 127;
    tile[c][w] = xb[(size_t)c * HWD * HWD + w];
  }
  __syncthreads();
  _Float16* xto = xt + (((size_t)b * HWD + h) * HWD) * NCH;
  #pragma unroll 4
  for (int i = 0; i < 32; ++i) {
    int idx = i * 256 + t;
    int c = idx & 63, w = idx >> 6;
    xto[(size_t)w * NCH + c] = (_Float16)tile[c][w];
  }
}

// ---- offset conv via MFMA: A = pixels (global, static shifts), B = weights (LDS). ----
#define OWROW 72    // padded weight row (64 halves + 8 pad)

__global__ __launch_bounds__(256) void off_conv_mfma_kernel(
    const _Float16* __restrict__ xt, const _Float16* __restrict__ wbo,
    const float* __restrict__ bo, float* __restrict__ off)
{
  __shared__ _Float16 wldsb[NK * 32 * OWROW];   // 41472 B

  int bid = blockIdx.x;
  int cid = (bid & 7) * 256 + (bid >> 3);   // XCD swizzle (bijective, 2048 % 8 == 0)
  int wseg = cid & 1;
  int h = (cid >> 1) & 127;
  int b = cid >> 8;
  int w0 = wseg * 64;

  int t = threadIdx.x;
  int lane = t & 63;
  int wv = t >> 6;

  int arow = wv * 16 + (lane & 15);
  int ahalf = (lane >> 4) * 8;

  // stage wbo -> padded LDS: 9*32 rows x 8 chunks = 2304 chunks / 256 = 9 iters
  #pragma unroll
  for (int i = 0; i < 9; ++i) {
    int idx = i * 256 + t;
    int row = idx >> 3, c8 = idx & 7;
    *(h16x8*)(wldsb + row * OWROW + c8 * 8) = *(const h16x8*)(wbo + row * 64 + c8 * 8);
  }
  __syncthreads();

  f32x4 acc[2];
  acc[0] = (f32x4){0.f, 0.f, 0.f, 0.f};
  acc[1] = (f32x4){0.f, 0.f, 0.f, 0.f};

  const _Float16* xtb = xt + ((size_t)b * HWD * HWD) * NCH;

  #pragma unroll
  for (int k = 0; k < NK; ++k) {
    int ky = k / 3, kx = k - ky * 3;
    int y = h - 1 + ky;
    int xx = w0 + arow - 1 + kx;
    bool ok = (y >= 0) & (y < HWD) & (xx >= 0) & (xx < HWD);
    int yc = min(max(y, 0), HWD - 1);
    int xc = min(max(xx, 0), HWD - 1);
    const _Float16* asrc = xtb + (size_t)(yc * HWD + xc) * NCH + ahalf;

    h16x8 afr[2];
    #pragma unroll
    for (int s = 0; s < 2; ++s) {
      h16x8 a = *(const h16x8*)(asrc + s * 32);
      if (!ok) {
        #pragma unroll
        for (int j = 0; j < 8; ++j) a[j] = (_Float16)0;
      }
      afr[s] = a;
    }

    #pragma unroll
    for (int nt = 0; nt < 2; ++nt) {
      int o = nt * 16 + (lane & 15);
      #pragma unroll
      for (int s = 0; s < 2; ++s) {
        h16x8 bfr = *(const h16x8*)(wldsb + (k * 32 + o) * OWROW + s * 32 + ahalf);
        acc[nt] = __builtin_amdgcn_mfma_f32_16x16x32_f16(afr[s], bfr, acc[nt], 0, 0, 0);
      }
    }
  }

  int pbase = w0 + wv * 16 + (lane >> 4) * 4;
  #pragma unroll
  for (int nt = 0; nt < 2; ++nt) {
    int o = nt * 16 + (lane & 15);
    if (o < 18) {
      float bias = bo[o];
      f32x4 r = acc[nt];
      r[0] += bias; r[1] += bias; r[2] += bias; r[3] += bias;
      float* dst = off + (((size_t)b * 18 + o) * HWD + h) * HWD + pbase;
      *(f32x4*)dst = r;
    }
  }
}

// ---- main deformable conv v6: 2x32 pixel patch per block; gather source staged
// in LDS halo tile (6x36 px, padded rows); weights in LDS (3-tap rolling stage);
// fp16 packed interp feeds MFMA B-frags directly. Global fallback for |off|>~1. ----
#define PXSTRIDE ((size_t)(HWD * HWD))
#define TR 6
#define TC 36
#define TPX (TR * TC)       // 216 pixels
#define PXS 72              // halves per pixel slot (64 + 8 pad)

__global__ __launch_bounds__(256, 2) void deform_main_kernel(
    const float* __restrict__ off, const _Float16* __restrict__ xt,
    const _Float16* __restrict__ wbt, float* __restrict__ out)
{
  __shared__ _Float16 xlds[TPX * PXS];      // 31104 B (reused as f32 epilogue buf)
  __shared__ _Float16 wlds[3 * 64 * PXS];   // 27648 B

  int bid = blockIdx.x;
  int cid = (bid & 7) * 256 + (bid >> 3);   // XCD swizzle (bijective, 2048 % 8 == 0)
  int wp = cid & 3;
  int hp = (cid >> 2) & 63;
  int b  = cid >> 8;
  int h0 = hp * 2, w0 = wp * 32;

  int t = threadIdx.x;
  int lane = t & 63;
  int wv = t >> 6;
  int pl = lane & 15;
  int cg = lane >> 4;
  int ch0 = cg * 8;
  int p  = wv * 16 + pl;          // pixel index in 2x32 patch
  int hh = p >> 5, ww = p & 31;
  int h = h0 + hh, w = w0 + ww;

  const _Float16* xtb = xt + ((size_t)b * HWD * HWD) * NCH;
  const float* offp = off + (size_t)b * 18 * PXSTRIDE + (size_t)h * HWD + w;

  // ---- hoist all 18 offset loads (latency overlaps staging) ----
  float oys[NK], oxs[NK];
  #pragma unroll
  for (int k = 0; k < NK; ++k) {
    oys[k] = offp[(size_t)(2 * k) * PXSTRIDE];
    oxs[k] = offp[(size_t)(2 * k + 1) * PXSTRIDE];
  }

  // ---- stage x halo tile: rows h0-2..h0+3, cols w0-2..w0+33 (clamped) ----
  #pragma unroll
  for (int i = 0; i < 7; ++i) {
    int idx = i * 256 + t;                  // < TPX*8 = 1728
    if (idx < TPX * 8) {
      int px = idx >> 3, c8 = idx & 7;
      int r = px / TC, c = px - r * TC;
      int yr = min(max(h0 - 2 + r, 0), HWD - 1);
      int xc = min(max(w0 - 2 + c, 0), HWD - 1);
      *(h16x8*)(xlds + px * PXS + c8 * 8) =
          *(const h16x8*)(xtb + (size_t)(yr * HWD + xc) * NCH + c8 * 8);
    }
  }

  // ---- weight stage: 3 taps (3*64 rows x 8 chunks = 1536 = 6 iters) ----
  auto stageW = [&](int g) {
    const _Float16* gsrc = wbt + (size_t)g * 3 * 64 * 64;
    #pragma unroll
    for (int i = 0; i < 6; ++i) {
      int idx = i * 256 + t;
      int row = idx >> 3, c8 = idx & 7;
      *(h16x8*)(wlds + row * PXS + c8 * 8) = *(const h16x8*)(gsrc + row * 64 + c8 * 8);
    }
  };

  f32x4 acc[4];
  #pragma unroll
  for (int nt = 0; nt < 4; ++nt) acc[nt] = (f32x4){0.f, 0.f, 0.f, 0.f};

  auto tap = [&](int k, int kloc) {
    int ky = k / 3, kx = k - ky * 3;
    float py = oys[k] + (float)(h - 1 + ky);
    float px = oxs[k] + (float)(w - 1 + kx);
    float y0f = floorf(py), x0f = floorf(px);
    float wy1 = py - y0f, wx1 = px - x0f;
    float wy0 = 1.f - wy1, wx0 = 1.f - wx1;
    int y0 = (int)y0f, x0 = (int)x0f;
    int sy = y0 - (h0 - 2);      // tile slot row of top corners
    int sx = x0 - (w0 - 2);      // tile slot col of left corners

    h16x8 s0, s1;
    #pragma unroll
    for (int j = 0; j < 8; ++j) { s0[j] = (_Float16)0; s1[j] = (_Float16)0; }

    #pragma unroll
    for (int r = 0; r < 4; ++r) {
      int dy = r >> 1, dx = r & 1;
      int yy = y0 + dy, xx = x0 + dx;
      int sr = sy + dy, sc = sx + dx;
      bool okimg = (yy >= 0) & (yy < HWD) & (xx >= 0) & (xx < HWD);
      float wtf = (dy ? wy1 : wy0) * (dx ? wx1 : wx0);
      wtf = okimg ? wtf : 0.f;
      _Float16 wzh = (_Float16)wtf;

      h16x8 g0, g1;
      bool intile = (sr >= 0) & (sr < TR) & (sc >= 0) & (sc < TC);
      if (intile) {
        const _Float16* sp = xlds + (sr * TC + sc) * PXS + ch0;
        g0 = *(const h16x8*)(sp);
        g1 = *(const h16x8*)(sp + 32);
      } else {
        // rare fallback (|offset| > ~1) or OOB-with-wt0; clamped safe read
        int yc = min(max(yy, 0), HWD - 1);
        int xc2 = min(max(xx, 0), HWD - 1);
        const _Float16* sp = xtb + (size_t)(yc * HWD + xc2) * NCH + ch0;
        g0 = *(const h16x8*)(sp);
        g1 = *(const h16x8*)(sp + 32);
      }
      h16x8 wzv;
      #pragma unroll
      for (int j = 0; j < 8; ++j) wzv[j] = wzh;
      s0 = g0 * wzv + s0;     // v_pk_fma_f16
      s1 = g1 * wzv + s1;
    }

    const _Float16* wk = wlds + kloc * (64 * PXS);
    #pragma unroll
    for (int nt = 0; nt < 4; ++nt) {
      int o = nt * 16 + pl;
      h16x8 a0 = *(const h16x8*)(wk + o * PXS + ch0);
      h16x8 a1 = *(const h16x8*)(wk + o * PXS + ch0 + 32);
      acc[nt] = __builtin_amdgcn_mfma_f32_16x16x32_f16(a0, s0, acc[nt], 0, 0, 0);
      acc[nt] = __builtin_amdgcn_mfma_f32_16x16x32_f16(a1, s1, acc[nt], 0, 0, 0);
    }
  };

  // ---- main loop: 3 weight stages x 3 taps ----
  stageW(0);
  __syncthreads();
  #pragma unroll
  for (int kk = 0; kk < 3; ++kk) tap(kk, kk);

  __syncthreads();
  stageW(1);
  __syncthreads();
  #pragma unroll
  for (int kk = 0; kk < 3; ++kk) tap(3 + kk, kk);

  __syncthreads();
  stageW(2);
  __syncthreads();
  #pragma unroll
  for (int kk = 0; kk < 3; ++kk) tap(6 + kk, kk);

  // ---- epilogue: D col=pixel p, row=oc. Stage via LDS for coalesced stores. ----
  __syncthreads();
  float* ost = (float*)xlds;   // [64 oc][65]
  #pragma unroll
  for (int nt = 0; nt < 4; ++nt) {
    int oc = nt * 16 + (lane >> 4) * 4;
    #pragma unroll
    for (int r = 0; r < 4; ++r)
      ost[(oc + r) * 65 + p] = acc[nt][r];
  }
  __syncthreads();
  #pragma unroll
  for (int i = 0; i < 16; ++i) {
    int idx = i * 256 + t;
    int pp = idx & 63, oc = idx >> 6;
    int hh2 = pp >> 5, ww2 = pp & 31;
    out[(((size_t)b * NCH + oc) * HWD + h0 + hh2) * HWD + w0 + ww2] = ost[oc * 65 + pp];
  }
}

extern "C" void kernel_launch(void* const* d_in, const int* in_sizes, int n_in,
                              void* d_out, int out_size, void* d_ws, size_t ws_size,
                              hipStream_t stream) {
  const float* x     = (const float*)d_in[0];
  const float* w_off = (const float*)d_in[1];
  const float* b_off = (const float*)d_in[2];
  const float* w_def = (const float*)d_in[3];
  float* out = (float*)d_out;

  char* ws = (char*)d_ws;
  float* off_ws   = (float*)ws;                          // 8*18*128*128*4 = 9,437,184 B
  _Float16* xt    = (_Float16*)(ws + 9437184);           // 8*128*128*64*2 = 16,777,216 B
  _Float16* wbt   = (_Float16*)(ws + 9437184 + 16777216);        // 9*64*64*2 = 73,728 B
  _Float16* wbo   = (_Float16*)(ws + 9437184 + 16777216 + 73728); // 9*32*64*2 = 36,864 B

  hipLaunchKernelGGL(prep_w_kernel,       dim3(144),  dim3(256), 0, stream, w_def, wbt);
  hipLaunchKernelGGL(prep_wo_kernel,      dim3(72),   dim3(256), 0, stream, w_off, wbo);
  hipLaunchKernelGGL(transpose_x_kernel,  dim3(1024), dim3(256), 0, stream, x, xt);
  hipLaunchKernelGGL(off_conv_mfma_kernel,dim3(2048), dim3(256), 0, stream, xt, wbo, b_off, off_ws);
  hipLaunchKernelGGL(deform_main_kernel,  dim3(2048), dim3(256), 0, stream, off_ws, xt, wbt, out);
}

// Round 7
// 65.176 us; speedup vs baseline: 3.0120x; 1.3267x over previous
//
#include <hip/hip_runtime.h>
#include <hip/hip_bf16.h>

#define HWD 128
#define NCH 64
#define NK  9

typedef __attribute__((ext_vector_type(8))) _Float16 h16x8;
typedef __attribute__((ext_vector_type(4))) float f32x4;

// ---- w_def [64 o][64 c][3][3] f32  ->  wbt [9 k][64 o][64 c] fp16 ----
__global__ void prep_w_kernel(const float* __restrict__ wd, _Float16* __restrict__ wbt) {
  int i = blockIdx.x * 256 + threadIdx.x;
  if (i >= NK * 64 * 64) return;
  int c = i & 63;
  int o = (i >> 6) & 63;
  int k = i >> 12;
  wbt[i] = (_Float16)wd[(o * 64 + c) * 9 + k];
}

// ---- w_off [18 o][64 c][3][3] f32 -> wbo [9 k][32 o_pad][64 c] fp16 ----
__global__ void prep_wo_kernel(const float* __restrict__ wo, _Float16* __restrict__ wbo) {
  int i = blockIdx.x * 256 + threadIdx.x;
  if (i >= NK * 32 * 64) return;
  int c = i & 63;
  int o = (i >> 6) & 31;
  int k = i >> 11;
  wbo[i] = (o < 18) ? (_Float16)wo[(o * 64 + c) * 9 + k] : (_Float16)0;
}

// ---- x NCHW f32 -> xt NHWC fp16 ----
__global__ __launch_bounds__(256) void transpose_x_kernel(const float* __restrict__ x,
                                                          _Float16* __restrict__ xt) {
  __shared__ float tile[64][129];
  int bid = blockIdx.x;
  int b = bid >> 7, h = bid & 127;
  int t = threadIdx.x;
  const float* xb = x + ((size_t)b * NCH) * HWD * HWD + (size_t)h * HWD;
  #pragma unroll 4
  for (int i = 0; i < 32; ++i) {
    int c = (t >> 7) + 2 * i;
    int w = t & 127;
    tile[c][w] = xb[(size_t)c * HWD * HWD + w];
  }
  __syncthreads();
  _Float16* xto = xt + (((size_t)b * HWD + h) * HWD) * NCH;
  #pragma unroll 4
  for (int i = 0; i < 32; ++i) {
    int idx = i * 256 + t;
    int c = idx & 63, w = idx >> 6;
    xto[(size_t)w * NCH + c] = (_Float16)tile[c][w];
  }
}

// ---- fused kernel v7: 4x16 pixel patch per block.
// Phase 1: offset conv (3x3, C64->18pad32) from the SAME x halo tile via MFMA,
//          offsets passed through LDS (no HBM round-trip).
// Phase 2: deformable conv, gather from halo tile, wbt 2-tap rolling stage.
// LDS: xlds 23.0K + wlds 18.4K + off_lds 4.9K = 46.3K -> 3 blocks/CU. ----
#define PH 4
#define PW 16
#define XR 8
#define XC 20
#define NSLOT (XR * XC)     // 160
#define PXS 72              // halves per slot/row (64 + 8 pad)

__global__ __launch_bounds__(256, 3) void fused_deform_kernel(
    const _Float16* __restrict__ xt, const _Float16* __restrict__ wbt,
    const _Float16* __restrict__ wbo, const float* __restrict__ bo,
    float* __restrict__ out)
{
  __shared__ _Float16 xlds[NSLOT * PXS];   // 23040 B (reused as f32 epilogue buf)
  __shared__ _Float16 wlds[128 * PXS];     // 18432 B (wbo 3-tap / wbt 2-tap stages)
  __shared__ float    off_lds[64 * 19];    //  4864 B

  int bid = blockIdx.x;
  int cid = (bid & 7) * 256 + (bid >> 3);  // XCD swizzle (bijective, 2048 % 8 == 0)
  int wp = cid & 7;
  int hp = (cid >> 3) & 31;
  int b  = cid >> 8;                       // = bid & 7 -> one image per XCD
  int h0 = hp * PH, w0 = wp * PW;

  int t = threadIdx.x;
  int lane = t & 63;
  int wv = t >> 6;
  int pl = lane & 15;
  int cg = lane >> 4;
  int ch0 = cg * 8;
  int p  = wv * 16 + pl;          // pixel index in 4x16 patch
  int hh = p >> 4, ww = p & 15;
  int h = h0 + hh, w = w0 + ww;

  const _Float16* xtb = xt + ((size_t)b * HWD * HWD) * NCH;

  // ---- stage x halo tile: rows h0-2..h0+5, cols w0-2..w0+17 (clamped) ----
  #pragma unroll
  for (int i = 0; i < 5; ++i) {
    int idx = i * 256 + t;                 // 160 slots * 8 chunks = 1280
    int px = idx >> 3, c8 = idx & 7;
    int r = px / XC, c = px - r * XC;
    int yr = min(max(h0 - 2 + r, 0), HWD - 1);
    int xc = min(max(w0 - 2 + c, 0), HWD - 1);
    *(h16x8*)(xlds + px * PXS + c8 * 8) =
        *(const h16x8*)(xtb + (size_t)(yr * HWD + xc) * NCH + c8 * 8);
  }

  // ---- weight stagers into wlds (padded rows) ----
  auto stage_wbo = [&](int g) {            // 3 taps x 32 rows = 96 rows
    const _Float16* gsrc = wbo + (size_t)g * 3 * 32 * 64;
    #pragma unroll
    for (int i = 0; i < 3; ++i) {
      int idx = i * 256 + t;
      int row = idx >> 3, c8 = idx & 7;
      *(h16x8*)(wlds + row * PXS + c8 * 8) = *(const h16x8*)(gsrc + row * 64 + c8 * 8);
    }
  };
  auto stage_wbt = [&](int k0, int ntaps) { // ntaps x 64 rows
    const _Float16* gsrc = wbt + (size_t)k0 * 64 * 64;
    for (int i = 0; i < ntaps * 2; ++i) {
      int idx = i * 256 + t;
      int row = idx >> 3, c8 = idx & 7;
      *(h16x8*)(wlds + row * PXS + c8 * 8) = *(const h16x8*)(gsrc + row * 64 + c8 * 8);
    }
  };

  // ======== PHASE 1: offset conv ========
  f32x4 acc2[2];
  acc2[0] = (f32x4){0.f, 0.f, 0.f, 0.f};
  acc2[1] = (f32x4){0.f, 0.f, 0.f, 0.f};

  auto tap1 = [&](int k, int kl) {
    int ky = k / 3, kx = k - ky * 3;
    int y = h + ky - 1, x = w + kx - 1;
    bool ok = (y >= 0) & (y < HWD) & (x >= 0) & (x < HWD);
    int srow = hh + ky + 1, scol = ww + kx + 1;
    const _Float16* sp = xlds + (srow * XC + scol) * PXS + ch0;
    h16x8 b0 = *(const h16x8*)(sp);
    h16x8 b1 = *(const h16x8*)(sp + 32);
    if (!ok) {
      #pragma unroll
      for (int j = 0; j < 8; ++j) { b0[j] = (_Float16)0; b1[j] = (_Float16)0; }
    }
    #pragma unroll
    for (int nt = 0; nt < 2; ++nt) {
      int row = kl * 32 + nt * 16 + pl;
      h16x8 a0 = *(const h16x8*)(wlds + row * PXS + ch0);
      h16x8 a1 = *(const h16x8*)(wlds + row * PXS + 32 + ch0);
      acc2[nt] = __builtin_amdgcn_mfma_f32_16x16x32_f16(a0, b0, acc2[nt], 0, 0, 0);
      acc2[nt] = __builtin_amdgcn_mfma_f32_16x16x32_f16(a1, b1, acc2[nt], 0, 0, 0);
    }
  };

  stage_wbo(0);
  __syncthreads();
  tap1(0, 0); tap1(1, 1); tap1(2, 2);
  __syncthreads();
  stage_wbo(1);
  __syncthreads();
  tap1(3, 0); tap1(4, 1); tap1(5, 2);
  __syncthreads();
  stage_wbo(2);
  __syncthreads();
  tap1(6, 0); tap1(7, 1); tap1(8, 2);

  // write offsets: D col=pixel (lane&15), row=oc (cg*4+r+16nt)
  #pragma unroll
  for (int nt = 0; nt < 2; ++nt) {
    #pragma unroll
    for (int r = 0; r < 4; ++r) {
      int oc = nt * 16 + cg * 4 + r;
      if (oc < 18)
        off_lds[p * 19 + oc] = acc2[nt][r] + bo[oc];
    }
  }
  __syncthreads();   // off_lds visible; phase-1 wlds reads done

  // ======== PHASE 2: deformable conv ========
  stage_wbt(0, 2);
  __syncthreads();

  float oys[NK], oxs[NK];
  #pragma unroll
  for (int k = 0; k < NK; ++k) {
    oys[k] = off_lds[p * 19 + 2 * k];
    oxs[k] = off_lds[p * 19 + 2 * k + 1];
  }

  f32x4 acc[4];
  #pragma unroll
  for (int nt = 0; nt < 4; ++nt) acc[nt] = (f32x4){0.f, 0.f, 0.f, 0.f};

  auto tap2 = [&](int k, int kl) {
    int ky = k / 3, kx = k - ky * 3;
    float py = oys[k] + (float)(h - 1 + ky);
    float px = oxs[k] + (float)(w - 1 + kx);
    float y0f = floorf(py), x0f = floorf(px);
    float wy1 = py - y0f, wx1 = px - x0f;
    float wy0 = 1.f - wy1, wx0 = 1.f - wx1;
    int y0 = (int)y0f, x0 = (int)x0f;
    int sy = y0 - (h0 - 2);
    int sx = x0 - (w0 - 2);

    h16x8 s0, s1;
    #pragma unroll
    for (int j = 0; j < 8; ++j) { s0[j] = (_Float16)0; s1[j] = (_Float16)0; }

    #pragma unroll
    for (int r = 0; r < 4; ++r) {
      int dy = r >> 1, dx = r & 1;
      int yy = y0 + dy, xx = x0 + dx;
      int sr = sy + dy, sc = sx + dx;
      bool okimg = (yy >= 0) & (yy < HWD) & (xx >= 0) & (xx < HWD);
      float wtf = (dy ? wy1 : wy0) * (dx ? wx1 : wx0);
      wtf = okimg ? wtf : 0.f;
      _Float16 wzh = (_Float16)wtf;

      h16x8 g0, g1;
      bool intile = (sr >= 0) & (sr < XR) & (sc >= 0) & (sc < XC);
      if (intile) {
        const _Float16* sp = xlds + (sr * XC + sc) * PXS + ch0;
        g0 = *(const h16x8*)(sp);
        g1 = *(const h16x8*)(sp + 32);
      } else {
        // rare fallback (|offset| > ~1) or OOB-with-wt0; clamped safe read
        int yc = min(max(yy, 0), HWD - 1);
        int xc2 = min(max(xx, 0), HWD - 1);
        const _Float16* sp = xtb + (size_t)(yc * HWD + xc2) * NCH + ch0;
        g0 = *(const h16x8*)(sp);
        g1 = *(const h16x8*)(sp + 32);
      }
      h16x8 wzv;
      #pragma unroll
      for (int j = 0; j < 8; ++j) wzv[j] = wzh;
      s0 = g0 * wzv + s0;     // v_pk_fma_f16
      s1 = g1 * wzv + s1;
    }

    const _Float16* wk = wlds + kl * (64 * PXS);
    #pragma unroll
    for (int nt = 0; nt < 4; ++nt) {
      int o = nt * 16 + pl;
      h16x8 a0 = *(const h16x8*)(wk + o * PXS + ch0);
      h16x8 a1 = *(const h16x8*)(wk + o * PXS + ch0 + 32);
      acc[nt] = __builtin_amdgcn_mfma_f32_16x16x32_f16(a0, s0, acc[nt], 0, 0, 0);
      acc[nt] = __builtin_amdgcn_mfma_f32_16x16x32_f16(a1, s1, acc[nt], 0, 0, 0);
    }
  };

  tap2(0, 0); tap2(1, 1);
  __syncthreads(); stage_wbt(2, 2); __syncthreads();
  tap2(2, 0); tap2(3, 1);
  __syncthreads(); stage_wbt(4, 2); __syncthreads();
  tap2(4, 0); tap2(5, 1);
  __syncthreads(); stage_wbt(6, 2); __syncthreads();
  tap2(6, 0); tap2(7, 1);
  __syncthreads(); stage_wbt(8, 1); __syncthreads();
  tap2(8, 0);

  // ---- epilogue: D col=pixel p, row=oc. Stage via LDS (reuse xlds). ----
  __syncthreads();
  float* ost = (float*)xlds;   // [64 oc][65] = 16640 B
  #pragma unroll
  for (int nt = 0; nt < 4; ++nt) {
    int oc = nt * 16 + cg * 4;
    #pragma unroll
    for (int r = 0; r < 4; ++r)
      ost[(oc + r) * 65 + p] = acc[nt][r];
  }
  __syncthreads();
  #pragma unroll
  for (int i = 0; i < 16; ++i) {
    int idx = i * 256 + t;
    int pp = idx & 63, oc = idx >> 6;
    int hh2 = pp >> 4, ww2 = pp & 15;
    out[(((size_t)b * NCH + oc) * HWD + h0 + hh2) * HWD + w0 + ww2] = ost[oc * 65 + pp];
  }
}

extern "C" void kernel_launch(void* const* d_in, const int* in_sizes, int n_in,
                              void* d_out, int out_size, void* d_ws, size_t ws_size,
                              hipStream_t stream) {
  const float* x     = (const float*)d_in[0];
  const float* w_off = (const float*)d_in[1];
  const float* b_off = (const float*)d_in[2];
  const float* w_def = (const float*)d_in[3];
  float* out = (float*)d_out;

  char* ws = (char*)d_ws;
  _Float16* xt  = (_Float16*)ws;                       // 8*128*128*64*2 = 16,777,216 B
  _Float16* wbt = (_Float16*)(ws + 16777216);          // 9*64*64*2      =     73,728 B
  _Float16* wbo = (_Float16*)(ws + 16777216 + 73728);  // 9*32*64*2      =     36,864 B

  hipLaunchKernelGGL(prep_w_kernel,      dim3(144),  dim3(256), 0, stream, w_def, wbt);
  hipLaunchKernelGGL(prep_wo_kernel,     dim3(72),   dim3(256), 0, stream, w_off, wbo);
  hipLaunchKernelGGL(transpose_x_kernel, dim3(1024), dim3(256), 0, stream, x, xt);
  hipLaunchKernelGGL(fused_deform_kernel,dim3(2048), dim3(256), 0, stream, xt, wbt, wbo, b_off, out);
}

// Round 8
// 55.486 us; speedup vs baseline: 3.5380x; 1.1746x over previous
//
#include <hip/hip_runtime.h>
#include <hip/hip_bf16.h>

#define HWD 128
#define NCH 64
#define NK  9

typedef __attribute__((ext_vector_type(8))) _Float16 h16x8;
typedef __attribute__((ext_vector_type(4))) float f32x4;

// async 16B global->LDS copy (dest = wave-uniform base + lane*16, linear)
__device__ __forceinline__ void async_copy16(void* lds, const void* g) {
  __builtin_amdgcn_global_load_lds(
      (const __attribute__((address_space(1))) unsigned int*)g,
      (__attribute__((address_space(3))) unsigned int*)lds, 16, 0, 0);
}

__device__ __forceinline__ int swz(int unit, int c) { return (c ^ unit) & 7; }

// ---- merged weight prep:
// w_def [64o][64c][3][3] f32 -> wbt [9k][64o][64c] fp16
// w_off [18o][64c][3][3] f32 -> wbo [9k][32o_pad][64c] fp16
__global__ void prep_weights_kernel(const float* __restrict__ wd,
                                    const float* __restrict__ wo,
                                    _Float16* __restrict__ wbt,
                                    _Float16* __restrict__ wbo) {
  int i = blockIdx.x * 256 + threadIdx.x;
  if (i < NK * 64 * 64) {
    int c = i & 63, o = (i >> 6) & 63, k = i >> 12;
    wbt[i] = (_Float16)wd[(o * 64 + c) * 9 + k];
  } else {
    int j = i - NK * 64 * 64;
    if (j < NK * 32 * 64) {
      int c = j & 63, o = (j >> 6) & 31, k = j >> 11;
      wbo[j] = (o < 18) ? (_Float16)wo[(o * 64 + c) * 9 + k] : (_Float16)0;
    }
  }
}

// ---- x NCHW f32 -> xt NHWC fp16 ----
__global__ __launch_bounds__(256) void transpose_x_kernel(const float* __restrict__ x,
                                                          _Float16* __restrict__ xt) {
  __shared__ float tile[64][129];
  int bid = blockIdx.x;
  int b = bid >> 7, h = bid & 127;
  int t = threadIdx.x;
  const float* xb = x + ((size_t)b * NCH) * HWD * HWD + (size_t)h * HWD;
  #pragma unroll 4
  for (int i = 0; i < 32; ++i) {
    int c = (t >> 7) + 2 * i;
    int w = t & 127;
    tile[c][w] = xb[(size_t)c * HWD * HWD + w];
  }
  __syncthreads();
  _Float16* xto = xt + (((size_t)b * HWD + h) * HWD) * NCH;
  #pragma unroll 4
  for (int i = 0; i < 32; ++i) {
    int idx = i * 256 + t;
    int c = idx & 63, w = idx >> 6;
    xto[(size_t)w * NCH + c] = (_Float16)tile[c][w];
  }
}

// ---- fused kernel v8: 4x16 patch. Swizzled unpadded LDS (39.2 KB -> 4 blk/CU),
// global_load_lds staging, per-tap double-buffered weights (stage k+1 || compute k).
#define PH 4
#define PW 16
#define XR 8
#define XC 20
#define NSLOT (XR * XC)     // 160 slots, 64 halves each (128 B)

__global__ __launch_bounds__(256, 4) void fused_deform_kernel(
    const _Float16* __restrict__ xt, const _Float16* __restrict__ wbt,
    const _Float16* __restrict__ wbo, const float* __restrict__ bo,
    float* __restrict__ out)
{
  __shared__ _Float16 xlds[NSLOT * 64];    // 20480 B (reused as f32 epilogue buf)
  __shared__ _Float16 wlds[2 * 64 * 64];   // 16384 B: two 8 KB weight buffers
  __shared__ _Float16 off_h[64 * 18];      //  2304 B: offsets, fp16

  int bid = blockIdx.x;
  int cid = (bid & 7) * 256 + (bid >> 3);  // XCD swizzle (bijective, 2048 % 8 == 0)
  int wp = cid & 7;
  int hp = (cid >> 3) & 31;
  int b  = cid >> 8;
  int h0 = hp * PH, w0 = wp * PW;

  int t = threadIdx.x;
  int lane = t & 63;
  int wv = t >> 6;
  int pl = lane & 15;
  int cg = lane >> 4;
  int p  = wv * 16 + pl;          // pixel index in 4x16 patch
  int hh = p >> 4, ww = p & 15;
  int h = h0 + hh, w = w0 + ww;

  const _Float16* xtb = xt + ((size_t)b * HWD * HWD) * NCH;

  // ---- stage x halo tile (async, source pre-swizzled, dest linear) ----
  #pragma unroll
  for (int i = 0; i < 5; ++i) {
    int idx = i * 256 + t;                 // 160 slots * 8 chunks = 1280
    int px = idx >> 3, c8 = idx & 7;
    int r = px / XC, c = px - r * XC;
    int yr = min(max(h0 - 2 + r, 0), HWD - 1);
    int xc = min(max(w0 - 2 + c, 0), HWD - 1);
    async_copy16(xlds + idx * 8,
                 xtb + (size_t)(yr * HWD + xc) * NCH + swz(px, c8) * 8);
  }

  // ---- weight stagers: one tap into buffer buf (async, swizzled source) ----
  auto stage_wbo_tap = [&](int k, int buf) {       // 32 rows x 8 chunks = 256
    int row = t >> 3, c8 = t & 7;
    async_copy16(wlds + buf * 4096 + t * 8,
                 wbo + ((size_t)k * 32 + row) * 64 + swz(row, c8) * 8);
  };
  auto stage_wbt_tap = [&](int k, int buf) {       // 64 rows x 8 chunks = 512
    #pragma unroll
    for (int i = 0; i < 2; ++i) {
      int idx = i * 256 + t;
      int row = idx >> 3, c8 = idx & 7;
      async_copy16(wlds + buf * 4096 + idx * 8,
                   wbt + ((size_t)k * 64 + row) * 64 + swz(row, c8) * 8);
    }
  };

  stage_wbo_tap(0, 0);
  __syncthreads();    // all staging (x halo + wbo tap0) complete

  // ======== PHASE 1: offset conv ========
  f32x4 acc2[2];
  acc2[0] = (f32x4){0.f, 0.f, 0.f, 0.f};
  acc2[1] = (f32x4){0.f, 0.f, 0.f, 0.f};

  auto tap1 = [&](int k, int buf) {
    int ky = k / 3, kx = k - ky * 3;
    int y = h + ky - 1, x = w + kx - 1;
    bool ok = (y >= 0) & (y < HWD) & (x >= 0) & (x < HWD);
    int slot = (hh + ky + 1) * XC + (ww + kx + 1);
    const _Float16* sp = xlds + slot * 64;
    h16x8 b0 = *(const h16x8*)(sp + swz(slot, cg) * 8);
    h16x8 b1 = *(const h16x8*)(sp + swz(slot, cg + 4) * 8);
    if (!ok) {
      #pragma unroll
      for (int j = 0; j < 8; ++j) { b0[j] = (_Float16)0; b1[j] = (_Float16)0; }
    }
    const _Float16* wb = wlds + buf * 4096;
    #pragma unroll
    for (int nt = 0; nt < 2; ++nt) {
      int row = nt * 16 + pl;
      h16x8 a0 = *(const h16x8*)(wb + row * 64 + swz(row, cg) * 8);
      h16x8 a1 = *(const h16x8*)(wb + row * 64 + swz(row, cg + 4) * 8);
      acc2[nt] = __builtin_amdgcn_mfma_f32_16x16x32_f16(a0, b0, acc2[nt], 0, 0, 0);
      acc2[nt] = __builtin_amdgcn_mfma_f32_16x16x32_f16(a1, b1, acc2[nt], 0, 0, 0);
    }
  };

  #pragma unroll
  for (int k = 0; k < NK; ++k) {
    if (k < NK - 1) stage_wbo_tap(k + 1, (k + 1) & 1);
    tap1(k, k & 1);
    __syncthreads();
  }

  // prefetch wbt tap0 into buf0 (last read of buf0 was tap1(8), barrier passed)
  stage_wbt_tap(0, 0);

  // write offsets (fp16): D col=pixel (lane&15), row=oc (cg*4+r+16nt)
  #pragma unroll
  for (int nt = 0; nt < 2; ++nt) {
    #pragma unroll
    for (int r = 0; r < 4; ++r) {
      int oc = nt * 16 + cg * 4 + r;
      if (oc < 18)
        off_h[p * 18 + oc] = (_Float16)(acc2[nt][r] + bo[oc]);
    }
  }
  __syncthreads();    // off_h visible + wbt tap0 staged

  // ======== PHASE 2: deformable conv ========
  float oys[NK], oxs[NK];
  #pragma unroll
  for (int k = 0; k < NK; ++k) {
    oys[k] = (float)off_h[p * 18 + 2 * k];
    oxs[k] = (float)off_h[p * 18 + 2 * k + 1];
  }

  f32x4 acc[4];
  #pragma unroll
  for (int nt = 0; nt < 4; ++nt) acc[nt] = (f32x4){0.f, 0.f, 0.f, 0.f};

  auto tap2 = [&](int k, int buf) {
    int ky = k / 3, kx = k - ky * 3;
    float py = oys[k] + (float)(h - 1 + ky);
    float px = oxs[k] + (float)(w - 1 + kx);
    float y0f = floorf(py), x0f = floorf(px);
    float wy1 = py - y0f, wx1 = px - x0f;
    float wy0 = 1.f - wy1, wx0 = 1.f - wx1;
    int y0 = (int)y0f, x0 = (int)x0f;
    int sy = y0 - (h0 - 2);
    int sx = x0 - (w0 - 2);

    h16x8 s0, s1;
    #pragma unroll
    for (int j = 0; j < 8; ++j) { s0[j] = (_Float16)0; s1[j] = (_Float16)0; }

    #pragma unroll
    for (int r = 0; r < 4; ++r) {
      int dy = r >> 1, dx = r & 1;
      int yy = y0 + dy, xx = x0 + dx;
      int sr = sy + dy, sc = sx + dx;
      bool okimg = (yy >= 0) & (yy < HWD) & (xx >= 0) & (xx < HWD);
      float wtf = (dy ? wy1 : wy0) * (dx ? wx1 : wx0);
      wtf = okimg ? wtf : 0.f;
      _Float16 wzh = (_Float16)wtf;

      h16x8 g0, g1;
      bool intile = (sr >= 0) & (sr < XR) & (sc >= 0) & (sc < XC);
      if (intile) {
        int slot = sr * XC + sc;
        const _Float16* sp = xlds + slot * 64;
        g0 = *(const h16x8*)(sp + swz(slot, cg) * 8);
        g1 = *(const h16x8*)(sp + swz(slot, cg + 4) * 8);
      } else {
        // rare fallback (|offset| > ~1) or OOB-with-wt0; clamped safe read
        int yc = min(max(yy, 0), HWD - 1);
        int xc2 = min(max(xx, 0), HWD - 1);
        const _Float16* sp = xtb + (size_t)(yc * HWD + xc2) * NCH + cg * 8;
        g0 = *(const h16x8*)(sp);
        g1 = *(const h16x8*)(sp + 32);
      }
      h16x8 wzv;
      #pragma unroll
      for (int j = 0; j < 8; ++j) wzv[j] = wzh;
      s0 = g0 * wzv + s0;     // v_pk_fma_f16
      s1 = g1 * wzv + s1;
    }

    const _Float16* wb = wlds + buf * 4096;
    #pragma unroll
    for (int nt = 0; nt < 4; ++nt) {
      int row = nt * 16 + pl;
      h16x8 a0 = *(const h16x8*)(wb + row * 64 + swz(row, cg) * 8);
      h16x8 a1 = *(const h16x8*)(wb + row * 64 + swz(row, cg + 4) * 8);
      acc[nt] = __builtin_amdgcn_mfma_f32_16x16x32_f16(a0, s0, acc[nt], 0, 0, 0);
      acc[nt] = __builtin_amdgcn_mfma_f32_16x16x32_f16(a1, s1, acc[nt], 0, 0, 0);
    }
  };

  #pragma unroll
  for (int k = 0; k < NK; ++k) {
    if (k < NK - 1) stage_wbt_tap(k + 1, (k + 1) & 1);
    tap2(k, k & 1);
    __syncthreads();
  }

  // ---- epilogue: D col=pixel p, row=oc. Stage via LDS (reuse xlds). ----
  float* ost = (float*)xlds;   // [64 oc][65] = 16640 B
  #pragma unroll
  for (int nt = 0; nt < 4; ++nt) {
    int oc = nt * 16 + cg * 4;
    #pragma unroll
    for (int r = 0; r < 4; ++r)
      ost[(oc + r) * 65 + p] = acc[nt][r];
  }
  __syncthreads();
  #pragma unroll
  for (int i = 0; i < 16; ++i) {
    int idx = i * 256 + t;
    int pp = idx & 63, oc = idx >> 6;
    int hh2 = pp >> 4, ww2 = pp & 15;
    out[(((size_t)b * NCH + oc) * HWD + h0 + hh2) * HWD + w0 + ww2] = ost[oc * 65 + pp];
  }
}

extern "C" void kernel_launch(void* const* d_in, const int* in_sizes, int n_in,
                              void* d_out, int out_size, void* d_ws, size_t ws_size,
                              hipStream_t stream) {
  const float* x     = (const float*)d_in[0];
  const float* w_off = (const float*)d_in[1];
  const float* b_off = (const float*)d_in[2];
  const float* w_def = (const float*)d_in[3];
  float* out = (float*)d_out;

  char* ws = (char*)d_ws;
  _Float16* xt  = (_Float16*)ws;                       // 8*128*128*64*2 = 16,777,216 B
  _Float16* wbt = (_Float16*)(ws + 16777216);          // 9*64*64*2      =     73,728 B
  _Float16* wbo = (_Float16*)(ws + 16777216 + 73728);  // 9*32*64*2      =     36,864 B

  hipLaunchKernelGGL(prep_weights_kernel, dim3(216),  dim3(256), 0, stream, w_def, w_off, wbt, wbo);
  hipLaunchKernelGGL(transpose_x_kernel,  dim3(1024), dim3(256), 0, stream, x, xt);
  hipLaunchKernelGGL(fused_deform_kernel, dim3(2048), dim3(256), 0, stream, xt, wbt, wbo, b_off, out);
}